// Round 4
// baseline (280.971 us; speedup 1.0000x reference)
//
#include <hip/hip_runtime.h>

// x:(1,64,64,768) -> n=4096 tokens, DIM=768, 12 heads x 64 dim
#define NTOK 4096
#define DIMD 768
#define NHD  12
#define HDD  64

typedef float f32x4 __attribute__((ext_vector_type(4)));
typedef short s16x8 __attribute__((ext_vector_type(8)));

#define MFMA16(a, b, c) __builtin_amdgcn_mfma_f32_16x16x32_bf16(a, b, c, 0, 0, 0)

__device__ inline short f2b(float f) {  // fp32 -> bf16 RNE
  unsigned u = __float_as_uint(f);
  u += 0x7FFFu + ((u >> 16) & 1u);
  return (short)(u >> 16);
}
__device__ inline float b2f(short s) {
  return __uint_as_float(((unsigned)(unsigned short)s) << 16);
}
__device__ inline void gl_lds16(const short* g, short* l) {
  __builtin_amdgcn_global_load_lds(
      (const __attribute__((address_space(1))) unsigned int*)g,
      (__attribute__((address_space(3))) unsigned int*)l, 16, 0, 0);
}

// ws layout (float units):
//   xaq    @0         (16384)
//   xav    @16384     (16384)
//   xb     @32768     (bf16 x)
//   wqkvb  @1605632   (bf16 Wqkv)
//   wpb    @2490368   (bf16 Wproj)
//   qkvb   @2785280   (bf16 [3][12][4096][64])
//   vtb    @7503872   (bf16 [12][64][4096])
//   attnb  @9076736   (bf16 [4096][768])

// ---------------------------------------------------------------------------
// Kernel 0: fp32 -> bf16 convert for Wqkv, Wproj only (x handled in k_lora)
#define N_WQ  1769472
#define N_WP  589824
__global__ __launch_bounds__(256)
void k_conv(const float* __restrict__ wq, const float* __restrict__ wp,
            short* __restrict__ wqb, short* __restrict__ wpb) {
  long e = (long)(blockIdx.x * 256 + threadIdx.x) * 4;
  const float* src; short* dst;
  if (e < N_WQ) { src = wq + e; dst = wqb + e; }
  else { src = wp + (e - N_WQ); dst = wpb + (e - N_WQ); }
  float4 v = *(const float4*)src;
  short4 b; b.x = f2b(v.x); b.y = f2b(v.y); b.z = f2b(v.z); b.w = f2b(v.w);
  *(short4*)dst = b;
}

// ---------------------------------------------------------------------------
// Kernel 1: xa_q = x @ A_q^T, xa_v = x @ A_v^T (fp32) + x -> bf16 conversion
__global__ __launch_bounds__(64)
void k_lora(const float* __restrict__ x, const float* __restrict__ Aq,
            const float* __restrict__ Av, float* __restrict__ xaq,
            float* __restrict__ xav, short* __restrict__ xb) {
  const int i = blockIdx.x;
  const int l = threadIdx.x;
  float xv[12];
#pragma unroll
  for (int k = 0; k < 12; ++k) xv[k] = x[i * DIMD + l + 64 * k];
#pragma unroll
  for (int k = 0; k < 12; ++k) xb[i * DIMD + l + 64 * k] = f2b(xv[k]);
#pragma unroll
  for (int o = 0; o < 8; ++o) {
    const float* A = (o < 4) ? (Aq + o * DIMD) : (Av + (o - 4) * DIMD);
    float acc = 0.f;
#pragma unroll
    for (int k = 0; k < 12; ++k) acc = fmaf(xv[k], A[l + 64 * k], acc);
#pragma unroll
    for (int off = 32; off; off >>= 1) acc += __shfl_xor(acc, off, 64);
    if (l == o) {
      if (o < 4) xaq[i * 4 + o] = acc;
      else       xav[i * 4 + (o - 4)] = acc;
    }
  }
}

// ---------------------------------------------------------------------------
// Kernel 2: bf16 MFMA qkv GEMM + bias + LoRA, scatter to qkvb[which][head][n][d]
__global__ __launch_bounds__(256)
void k_qkv(const short* __restrict__ xb, const short* __restrict__ wb,
           const float* __restrict__ bqkv, const float* __restrict__ Bq,
           const float* __restrict__ Bv, const float* __restrict__ xaq,
           const float* __restrict__ xav, short* __restrict__ qkvb) {
  const int j0 = blockIdx.x * 128;
  const int i0 = blockIdx.y * 128;
  __shared__ short As[128 * 32];
  __shared__ short Bs[128 * 32];
  const int t = threadIdx.x, lane = t & 63, w = t >> 6;
  const int l15 = lane & 15, quad = lane >> 4;
  const int wm = w >> 1, wn = w & 1;

  f32x4 acc[4][4];
#pragma unroll
  for (int a = 0; a < 4; ++a)
#pragma unroll
    for (int b = 0; b < 4; ++b) acc[a][b] = (f32x4){0.f, 0.f, 0.f, 0.f};

  for (int kk = 0; kk < DIMD; kk += 32) {
    __syncthreads();
#pragma unroll
    for (int rep = 0; rep < 2; ++rep) {
      int c = rep * 256 + w * 64 + lane;
      gl_lds16(xb + (size_t)(i0 + (c >> 2)) * DIMD + kk + (c & 3) * 8,
               &As[(rep * 256 + w * 64) * 8]);
      gl_lds16(wb + (size_t)(j0 + (c >> 2)) * DIMD + kk + (c & 3) * 8,
               &Bs[(rep * 256 + w * 64) * 8]);
    }
    __syncthreads();
    s16x8 af[4], bf[4];
#pragma unroll
    for (int mt = 0; mt < 4; ++mt)
      af[mt] = *(const s16x8*)&As[(wm * 64 + mt * 16 + l15) * 32 + quad * 8];
#pragma unroll
    for (int nt = 0; nt < 4; ++nt)
      bf[nt] = *(const s16x8*)&Bs[(wn * 64 + nt * 16 + l15) * 32 + quad * 8];
#pragma unroll
    for (int mt = 0; mt < 4; ++mt)
#pragma unroll
      for (int nt = 0; nt < 4; ++nt)
        acc[mt][nt] = MFMA16(af[mt], bf[nt], acc[mt][nt]);
  }

  const int which = j0 / DIMD;
  float bj[4]; int jj[4], head[4], dd[4];
#pragma unroll
  for (int nt = 0; nt < 4; ++nt) {
    int j = j0 + wn * 64 + nt * 16 + l15;
    bj[nt] = bqkv[j];
    jj[nt] = j - which * DIMD;
    head[nt] = jj[nt] >> 6;
    dd[nt] = jj[nt] & 63;
  }
#pragma unroll
  for (int mt = 0; mt < 4; ++mt)
#pragma unroll
    for (int r = 0; r < 4; ++r) {
      const int i = i0 + wm * 64 + mt * 16 + quad * 4 + r;
      float aq0 = 0, aq1 = 0, aq2 = 0, aq3 = 0;
      if (which == 0) {
        const float* a = xaq + i * 4;
        aq0 = a[0]; aq1 = a[1]; aq2 = a[2]; aq3 = a[3];
      } else if (which == 2) {
        const float* a = xav + i * 4;
        aq0 = a[0]; aq1 = a[1]; aq2 = a[2]; aq3 = a[3];
      }
#pragma unroll
      for (int nt = 0; nt < 4; ++nt) {
        float v = acc[mt][nt][r] + bj[nt];
        if (which == 0) {
          const float* B = Bq + jj[nt] * 4;
          v += 0.25f * (aq0 * B[0] + aq1 * B[1] + aq2 * B[2] + aq3 * B[3]);
        } else if (which == 2) {
          const float* B = Bv + jj[nt] * 4;
          v += 0.25f * (aq0 * B[0] + aq1 * B[1] + aq2 * B[2] + aq3 * B[3]);
        }
        qkvb[(((size_t)which * NHD + head[nt]) * NTOK + i) * HDD + dd[nt]] = f2b(v);
      }
    }
}

// ---------------------------------------------------------------------------
// Kernel 3: transpose V: qkvb[2][head][n][d] -> vtb[head][d][n]
__global__ __launch_bounds__(256)
void k_vt(const short* __restrict__ qkvb, short* __restrict__ vtb) {
  const int head = blockIdx.y;
  const int n0 = blockIdx.x * 64;
  const short* vg = qkvb + ((size_t)(2 * NHD + head)) * NTOK * HDD;
  __shared__ short T[64][68];
  const int t = threadIdx.x;
#pragma unroll
  for (int rp = 0; rp < 4; ++rp) {
    int f = t + 256 * rp;
    int n = f >> 4, c4 = (f & 15) * 4;
    *(short4*)&T[n][c4] = *(const short4*)&vg[(size_t)(n0 + n) * HDD + c4];
  }
  __syncthreads();
#pragma unroll
  for (int rp = 0; rp < 4; ++rp) {
    int f = t + 256 * rp;
    int d = f >> 4, n4 = (f & 15) * 4;
    short4 o;
    o.x = T[n4 + 0][d]; o.y = T[n4 + 1][d];
    o.z = T[n4 + 2][d]; o.w = T[n4 + 3][d];
    *(short4*)&vtb[((size_t)head * HDD + d) * NTOK + n0 + n4] = o;
  }
}

// ---------------------------------------------------------------------------
// Kernel 4: MFMA bf16 flash attention; fused rel-pos bias; fixed-max softmax;
// register-pipelined K/V staging; XOR-swizzled P round-trip.
// grid (64 qblocks, 12 heads), 256 threads = 4 waves x 16 query rows.
// LDS (shorts): Ks[64][72]@0, Vt[64][72]@4608, Ps[64][72]@9216 (swizzled),
//               bH[64][66]@13824, bW[64][66]@18048; RW overlay @4608
__global__ __launch_bounds__(256)
void k_attn2(const short* __restrict__ qkvb, const short* __restrict__ vtb,
             const float* __restrict__ relh, const float* __restrict__ relw,
             short* __restrict__ attnb) {
  const int head = blockIdx.y;
  const int hq = blockIdx.x;
  const int n0 = hq * 64;

  __shared__ short sm[22272];
  short* Ks = sm;
  short* Vt = sm + 4608;
  short* Ps = sm + 9216;
  short* bH = sm + 13824;
  short* bW = sm + 18048;
  short* RW = sm + 4608;

  const short* qg = qkvb + (size_t)(0 * NHD + head) * NTOK * HDD;
  const short* kg = qkvb + (size_t)(1 * NHD + head) * NTOK * HDD;
  const short* vtg = vtb + (size_t)head * HDD * NTOK;

  const int t = threadIdx.x;
  const int w = t >> 6, lane = t & 63;
  const int l15 = lane & 15, quad = lane >> 4;
  const int q0w = w * 16;

  // staging coordinates (each thread owns 2 rows x 8 shorts of K and Vt)
  const int sa0 = t >> 3, sc0 = (t & 7) * 8;
  const int sa1 = sa0 + 32;

  // ---- issue tile-0 K/V loads immediately (latency hidden by prologue) ----
  s16x8 kr0 = *(const s16x8*)&kg[(size_t)sa0 * HDD + sc0];
  s16x8 kr1 = *(const s16x8*)&kg[(size_t)sa1 * HDD + sc0];
  s16x8 vr0 = *(const s16x8*)&vtg[(size_t)sa0 * NTOK + sc0];
  s16x8 vr1 = *(const s16x8*)&vtg[(size_t)sa1 * NTOK + sc0];

  // ---- prologue: stage RH -> Ks, RW -> overlay ----
#pragma unroll
  for (int rp = 0; rp < 2; ++rp) {
    int f = t + 256 * rp;
    int kt = f >> 3, c = (f & 7) * 8;
    const float* src = relh + (size_t)(hq + 63 - kt) * HDD + c;
    float4 v0 = *(const float4*)src, v1 = *(const float4*)(src + 4);
    short4 b0, b1;
    b0.x = f2b(v0.x); b0.y = f2b(v0.y); b0.z = f2b(v0.z); b0.w = f2b(v0.w);
    b1.x = f2b(v1.x); b1.y = f2b(v1.y); b1.z = f2b(v1.z); b1.w = f2b(v1.w);
    *(short4*)&Ks[kt * 72 + c] = b0;
    *(short4*)&Ks[kt * 72 + c + 4] = b1;
  }
#pragma unroll
  for (int rp = 0; rp < 4; ++rp) {
    int f = t + 256 * rp;
    int d = f >> 3, c = (f & 7) * 8;
    float4 v0 = make_float4(0, 0, 0, 0), v1 = make_float4(0, 0, 0, 0);
    if (d < 127) {
      const float* src = relw + (size_t)d * HDD + c;
      v0 = *(const float4*)src; v1 = *(const float4*)(src + 4);
    }
    short4 b0, b1;
    b0.x = f2b(v0.x); b0.y = f2b(v0.y); b0.z = f2b(v0.z); b0.w = f2b(v0.w);
    b1.x = f2b(v1.x); b1.y = f2b(v1.y); b1.z = f2b(v1.z); b1.w = f2b(v1.w);
    *(short4*)&RW[d * 72 + c] = b0;
    *(short4*)&RW[d * 72 + c + 4] = b1;
  }

  s16x8 qa[2];
  qa[0] = *(const s16x8*)&qg[(size_t)(n0 + q0w + l15) * HDD + quad * 8];
  qa[1] = *(const s16x8*)&qg[(size_t)(n0 + q0w + l15) * HDD + 32 + quad * 8];
  __syncthreads();

  {  // bH = Q @ RH^T
    f32x4 hc[4];
#pragma unroll
    for (int nt = 0; nt < 4; ++nt) hc[nt] = (f32x4){0.f, 0.f, 0.f, 0.f};
#pragma unroll
    for (int s = 0; s < 2; ++s)
#pragma unroll
      for (int nt = 0; nt < 4; ++nt) {
        s16x8 b = *(const s16x8*)&Ks[(16 * nt + l15) * 72 + 32 * s + quad * 8];
        hc[nt] = MFMA16(qa[s], b, hc[nt]);
      }
#pragma unroll
    for (int nt = 0; nt < 4; ++nt)
#pragma unroll
      for (int r = 0; r < 4; ++r)
        bH[(q0w + 4 * quad + r) * 66 + 16 * nt + l15] = f2b(hc[nt][r]);
  }
  {  // bW via M = Q @ relw^T, gather j = wq + 63 - d
    f32x4 mc[8];
#pragma unroll
    for (int nt = 0; nt < 8; ++nt) mc[nt] = (f32x4){0.f, 0.f, 0.f, 0.f};
#pragma unroll
    for (int s = 0; s < 2; ++s)
#pragma unroll
      for (int nt = 0; nt < 8; ++nt) {
        s16x8 b = *(const s16x8*)&RW[(16 * nt + l15) * 72 + 32 * s + quad * 8];
        mc[nt] = MFMA16(qa[s], b, mc[nt]);
      }
#pragma unroll
    for (int nt = 0; nt < 8; ++nt)
#pragma unroll
      for (int r = 0; r < 4; ++r) {
        int wq = q0w + 4 * quad + r;
        int d = 16 * nt + l15;
        int j = wq + 63 - d;
        if (j >= 0 && j < 64) bW[wq * 66 + j] = f2b(mc[nt][r]);
      }
  }
  // bW/bH are written and read by the same wave -> no barrier needed here.
  // (ln2 folded: softmax uses exp2)
  float bwreg[16];
#pragma unroll
  for (int nt = 0; nt < 4; ++nt)
#pragma unroll
    for (int r = 0; r < 4; ++r)
      bwreg[nt * 4 + r] =
          b2f(bW[(q0w + 4 * quad + r) * 66 + 16 * nt + l15]) * 1.44269504f;

  float ps[4] = {0.f, 0.f, 0.f, 0.f};
  f32x4 oc[4];
#pragma unroll
  for (int nt = 0; nt < 4; ++nt) oc[nt] = (f32x4){0.f, 0.f, 0.f, 0.f};

  const int pswz = quad * 8;             // write-side column swizzle
  const int prsw = (l15 & 12) * 2;       // read-side column swizzle

  for (int kt = 0; kt < 64; ++kt) {
    __syncthreads();  // readers of previous tile (and bias prologue) done
    *(s16x8*)&Ks[sa0 * 72 + sc0] = kr0;
    *(s16x8*)&Ks[sa1 * 72 + sc0] = kr1;
    *(s16x8*)&Vt[sa0 * 72 + sc0] = vr0;
    *(s16x8*)&Vt[sa1 * 72 + sc0] = vr1;
    __syncthreads();

    // issue next tile's loads; consumed after the NEXT barrier (latency hidden)
    if (kt < 63) {
      const int nk = (kt + 1) * 64;
      kr0 = *(const s16x8*)&kg[(size_t)(nk + sa0) * HDD + sc0];
      kr1 = *(const s16x8*)&kg[(size_t)(nk + sa1) * HDD + sc0];
      vr0 = *(const s16x8*)&vtg[(size_t)sa0 * NTOK + nk + sc0];
      vr1 = *(const s16x8*)&vtg[(size_t)sa1 * NTOK + nk + sc0];
    }

    // S = Q K^T
    f32x4 sc[4];
#pragma unroll
    for (int nt = 0; nt < 4; ++nt) sc[nt] = (f32x4){0.f, 0.f, 0.f, 0.f};
#pragma unroll
    for (int s = 0; s < 2; ++s)
#pragma unroll
      for (int nt = 0; nt < 4; ++nt) {
        s16x8 b = *(const s16x8*)&Ks[(16 * nt + l15) * 72 + 32 * s + quad * 8];
        sc[nt] = MFMA16(qa[s], b, sc[nt]);
      }

    // fixed-max softmax in exp2 domain: p = 2^(S*(1/8*log2e) + (bh+bw)*log2e)
    float bh[4];
#pragma unroll
    for (int r = 0; r < 4; ++r)
      bh[r] = b2f(bH[(q0w + 4 * quad + r) * 66 + kt]) * 1.44269504f;
#pragma unroll
    for (int nt = 0; nt < 4; ++nt)
#pragma unroll
      for (int r = 0; r < 4; ++r) {
        float sv = fmaf(0.18033688f, sc[nt][r], bh[r] + bwreg[nt * 4 + r]);
        float p = exp2f(sv);
        ps[r] += p;
        Ps[(q0w + 4 * quad + r) * 72 + ((16 * nt + l15) ^ pswz)] =
            (short)(__float_as_uint(p) >> 16);
      }

    // O += P @ V  (swizzled A-frag read; Vt rows as B-frags; all b128)
#pragma unroll
    for (int s = 0; s < 2; ++s) {
      s16x8 pa =
          *(const s16x8*)&Ps[(q0w + l15) * 72 + ((32 * s + quad * 8) ^ prsw)];
#pragma unroll
      for (int nt = 0; nt < 4; ++nt) {
        s16x8 vb = *(const s16x8*)&Vt[(16 * nt + l15) * 72 + 32 * s + quad * 8];
        oc[nt] = MFMA16(pa, vb, oc[nt]);
      }
    }
  }

  // final row-sum reduction across the 16 l15 lanes, then write bf16
#pragma unroll
  for (int r = 0; r < 4; ++r) {
#pragma unroll
    for (int off = 1; off < 16; off <<= 1) ps[r] += __shfl_xor(ps[r], off, 64);
    ps[r] = 1.f / ps[r];
  }
#pragma unroll
  for (int nt = 0; nt < 4; ++nt)
#pragma unroll
    for (int r = 0; r < 4; ++r) {
      int q = q0w + 4 * quad + r;
      attnb[(size_t)(n0 + q) * DIMD + head * 64 + 16 * nt + l15] =
          f2b(oc[nt][r] * ps[r]);
    }
}

// ---------------------------------------------------------------------------
// Kernel 5: bf16 MFMA proj: out = attn @ Wp^T + bp (fp32 out)
__global__ __launch_bounds__(256)
void k_proj(const short* __restrict__ ab, const short* __restrict__ wpb,
            const float* __restrict__ bp, float* __restrict__ out) {
  const int j0 = blockIdx.x * 64;
  const int i0 = blockIdx.y * 128;
  __shared__ short As[128 * 32];
  __shared__ short Bs[64 * 32];
  const int t = threadIdx.x, lane = t & 63, w = t >> 6;
  const int l15 = lane & 15, quad = lane >> 4;
  const int wm = w >> 1, wn = w & 1;

  f32x4 acc[4][2];
#pragma unroll
  for (int a = 0; a < 4; ++a)
#pragma unroll
    for (int b = 0; b < 2; ++b) acc[a][b] = (f32x4){0.f, 0.f, 0.f, 0.f};

  for (int kk = 0; kk < DIMD; kk += 32) {
    __syncthreads();
#pragma unroll
    for (int rep = 0; rep < 2; ++rep) {
      int c = rep * 256 + w * 64 + lane;
      gl_lds16(ab + (size_t)(i0 + (c >> 2)) * DIMD + kk + (c & 3) * 8,
               &As[(rep * 256 + w * 64) * 8]);
    }
    {
      gl_lds16(wpb + (size_t)(j0 + ((w * 64 + lane) >> 2)) * DIMD + kk +
                   ((w * 64 + lane) & 3) * 8,
               &Bs[(w * 64) * 8]);
    }
    __syncthreads();
    s16x8 af[4], bf[2];
#pragma unroll
    for (int mt = 0; mt < 4; ++mt)
      af[mt] = *(const s16x8*)&As[(wm * 64 + mt * 16 + l15) * 32 + quad * 8];
#pragma unroll
    for (int nt = 0; nt < 2; ++nt)
      bf[nt] = *(const s16x8*)&Bs[(wn * 32 + nt * 16 + l15) * 32 + quad * 8];
#pragma unroll
    for (int mt = 0; mt < 4; ++mt)
#pragma unroll
      for (int nt = 0; nt < 2; ++nt)
        acc[mt][nt] = MFMA16(af[mt], bf[nt], acc[mt][nt]);
  }

#pragma unroll
  for (int mt = 0; mt < 4; ++mt)
#pragma unroll
    for (int r = 0; r < 4; ++r) {
      const int i = i0 + wm * 64 + mt * 16 + quad * 4 + r;
#pragma unroll
      for (int nt = 0; nt < 2; ++nt) {
        const int j = j0 + wn * 32 + nt * 16 + l15;
        out[(size_t)i * DIMD + j] = acc[mt][nt][r] + bp[j];
      }
    }
}

// ---------------------------------------------------------------------------
extern "C" void kernel_launch(void* const* d_in, const int* in_sizes, int n_in,
                              void* d_out, int out_size, void* d_ws, size_t ws_size,
                              hipStream_t stream) {
  (void)in_sizes; (void)n_in; (void)out_size; (void)ws_size;
  const float* x    = (const float*)d_in[0];
  const float* Wqkv = (const float*)d_in[1];
  const float* bqkv = (const float*)d_in[2];
  const float* Aq   = (const float*)d_in[3];
  const float* Bq   = (const float*)d_in[4];
  const float* Av   = (const float*)d_in[5];
  const float* Bv   = (const float*)d_in[6];
  const float* relh = (const float*)d_in[7];
  const float* relw = (const float*)d_in[8];
  const float* Wp   = (const float*)d_in[9];
  const float* bp   = (const float*)d_in[10];
  float* out = (float*)d_out;

  float* ws = (float*)d_ws;
  float* xaq  = ws;
  float* xav  = ws + 16384;
  short* xb    = (short*)(ws + 32768);
  short* wqkvb = (short*)(ws + 1605632);
  short* wpb   = (short*)(ws + 2490368);
  short* qkvb  = (short*)(ws + 2785280);
  short* vtb   = (short*)(ws + 7503872);
  short* attnb = (short*)(ws + 9076736);

  k_conv<<<dim3(2304), dim3(256), 0, stream>>>(Wqkv, Wp, wqkvb, wpb);
  k_lora<<<dim3(NTOK), dim3(64), 0, stream>>>(x, Aq, Av, xaq, xav, xb);
  k_qkv<<<dim3(18, 32), dim3(256), 0, stream>>>(xb, wqkvb, bqkv, Bq, Bv, xaq,
                                                xav, qkvb);
  k_vt<<<dim3(64, NHD), dim3(256), 0, stream>>>(qkvb, vtb);
  k_attn2<<<dim3(64, NHD), dim3(256), 0, stream>>>(qkvb, vtb, relh, relw, attnb);
  k_proj<<<dim3(12, 32), dim3(256), 0, stream>>>(attnb, wpb, bp, out);
}

// Round 5
// 262.745 us; speedup vs baseline: 1.0694x; 1.0694x over previous
//
#include <hip/hip_runtime.h>

// x:(1,64,64,768) -> n=4096 tokens, DIM=768, 12 heads x 64 dim
#define NTOK 4096
#define DIMD 768
#define NHD  12
#define HDD  64

typedef float  f32x4  __attribute__((ext_vector_type(4)));
typedef float  f32x16 __attribute__((ext_vector_type(16)));
typedef short  s16x8  __attribute__((ext_vector_type(8)));

#define MFMA16(a, b, c) __builtin_amdgcn_mfma_f32_16x16x32_bf16(a, b, c, 0, 0, 0)
#define MFMA32(a, b, c) __builtin_amdgcn_mfma_f32_32x32x16_bf16(a, b, c, 0, 0, 0)

__device__ inline short f2b(float f) {  // fp32 -> bf16 RNE
  unsigned u = __float_as_uint(f);
  u += 0x7FFFu + ((u >> 16) & 1u);
  return (short)(u >> 16);
}
__device__ inline float b2f(short s) {
  return __uint_as_float(((unsigned)(unsigned short)s) << 16);
}
__device__ inline void gl_lds16(const short* g, short* l) {
  __builtin_amdgcn_global_load_lds(
      (const __attribute__((address_space(1))) unsigned int*)g,
      (__attribute__((address_space(3))) unsigned int*)l, 16, 0, 0);
}

// ws layout (float units):
//   xaq @0, xav @16384, xb @32768, wqkvb @1605632, wpb @2490368,
//   qkvb @2785280, vtb @7503872, attnb @9076736

// ---------------------------------------------------------------------------
// Kernel 0: fp32 -> bf16 convert for Wqkv, Wproj
#define N_WQ  1769472
#define N_WP  589824
__global__ __launch_bounds__(256)
void k_conv(const float* __restrict__ wq, const float* __restrict__ wp,
            short* __restrict__ wqb, short* __restrict__ wpb) {
  long e = (long)(blockIdx.x * 256 + threadIdx.x) * 4;
  const float* src; short* dst;
  if (e < N_WQ) { src = wq + e; dst = wqb + e; }
  else { src = wp + (e - N_WQ); dst = wpb + (e - N_WQ); }
  float4 v = *(const float4*)src;
  short4 b; b.x = f2b(v.x); b.y = f2b(v.y); b.z = f2b(v.z); b.w = f2b(v.w);
  *(short4*)dst = b;
}

// ---------------------------------------------------------------------------
// Kernel 1: xa_q = x @ A_q^T, xa_v = x @ A_v^T (fp32) + x -> bf16
__global__ __launch_bounds__(64)
void k_lora(const float* __restrict__ x, const float* __restrict__ Aq,
            const float* __restrict__ Av, float* __restrict__ xaq,
            float* __restrict__ xav, short* __restrict__ xb) {
  const int i = blockIdx.x;
  const int l = threadIdx.x;
  float xv[12];
#pragma unroll
  for (int k = 0; k < 12; ++k) xv[k] = x[i * DIMD + l + 64 * k];
#pragma unroll
  for (int k = 0; k < 12; ++k) xb[i * DIMD + l + 64 * k] = f2b(xv[k]);
#pragma unroll
  for (int o = 0; o < 8; ++o) {
    const float* A = (o < 4) ? (Aq + o * DIMD) : (Av + (o - 4) * DIMD);
    float acc = 0.f;
#pragma unroll
    for (int k = 0; k < 12; ++k) acc = fmaf(xv[k], A[l + 64 * k], acc);
#pragma unroll
    for (int off = 32; off; off >>= 1) acc += __shfl_xor(acc, off, 64);
    if (l == o) {
      if (o < 4) xaq[i * 4 + o] = acc;
      else       xav[i * 4 + (o - 4)] = acc;
    }
  }
}

// ---------------------------------------------------------------------------
// Kernel 2: bf16 MFMA qkv GEMM + bias + LoRA, scatter to qkvb[which][head][n][d]
__global__ __launch_bounds__(256)
void k_qkv(const short* __restrict__ xb, const short* __restrict__ wb,
           const float* __restrict__ bqkv, const float* __restrict__ Bq,
           const float* __restrict__ Bv, const float* __restrict__ xaq,
           const float* __restrict__ xav, short* __restrict__ qkvb) {
  const int j0 = blockIdx.x * 128;
  const int i0 = blockIdx.y * 128;
  __shared__ short As[128 * 32];
  __shared__ short Bs[128 * 32];
  const int t = threadIdx.x, lane = t & 63, w = t >> 6;
  const int l15 = lane & 15, quad = lane >> 4;
  const int wm = w >> 1, wn = w & 1;

  f32x4 acc[4][4];
#pragma unroll
  for (int a = 0; a < 4; ++a)
#pragma unroll
    for (int b = 0; b < 4; ++b) acc[a][b] = (f32x4){0.f, 0.f, 0.f, 0.f};

  for (int kk = 0; kk < DIMD; kk += 32) {
    __syncthreads();
#pragma unroll
    for (int rep = 0; rep < 2; ++rep) {
      int c = rep * 256 + w * 64 + lane;
      gl_lds16(xb + (size_t)(i0 + (c >> 2)) * DIMD + kk + (c & 3) * 8,
               &As[(rep * 256 + w * 64) * 8]);
      gl_lds16(wb + (size_t)(j0 + (c >> 2)) * DIMD + kk + (c & 3) * 8,
               &Bs[(rep * 256 + w * 64) * 8]);
    }
    __syncthreads();
    s16x8 af[4], bf[4];
#pragma unroll
    for (int mt = 0; mt < 4; ++mt)
      af[mt] = *(const s16x8*)&As[(wm * 64 + mt * 16 + l15) * 32 + quad * 8];
#pragma unroll
    for (int nt = 0; nt < 4; ++nt)
      bf[nt] = *(const s16x8*)&Bs[(wn * 64 + nt * 16 + l15) * 32 + quad * 8];
#pragma unroll
    for (int mt = 0; mt < 4; ++mt)
#pragma unroll
      for (int nt = 0; nt < 4; ++nt)
        acc[mt][nt] = MFMA16(af[mt], bf[nt], acc[mt][nt]);
  }

  const int which = j0 / DIMD;
  float bj[4]; int jj[4], head[4], dd[4];
#pragma unroll
  for (int nt = 0; nt < 4; ++nt) {
    int j = j0 + wn * 64 + nt * 16 + l15;
    bj[nt] = bqkv[j];
    jj[nt] = j - which * DIMD;
    head[nt] = jj[nt] >> 6;
    dd[nt] = jj[nt] & 63;
  }
#pragma unroll
  for (int mt = 0; mt < 4; ++mt)
#pragma unroll
    for (int r = 0; r < 4; ++r) {
      const int i = i0 + wm * 64 + mt * 16 + quad * 4 + r;
      float aq0 = 0, aq1 = 0, aq2 = 0, aq3 = 0;
      if (which == 0) {
        const float* a = xaq + i * 4;
        aq0 = a[0]; aq1 = a[1]; aq2 = a[2]; aq3 = a[3];
      } else if (which == 2) {
        const float* a = xav + i * 4;
        aq0 = a[0]; aq1 = a[1]; aq2 = a[2]; aq3 = a[3];
      }
#pragma unroll
      for (int nt = 0; nt < 4; ++nt) {
        float v = acc[mt][nt][r] + bj[nt];
        if (which == 0) {
          const float* B = Bq + jj[nt] * 4;
          v += 0.25f * (aq0 * B[0] + aq1 * B[1] + aq2 * B[2] + aq3 * B[3]);
        } else if (which == 2) {
          const float* B = Bv + jj[nt] * 4;
          v += 0.25f * (aq0 * B[0] + aq1 * B[1] + aq2 * B[2] + aq3 * B[3]);
        }
        qkvb[(((size_t)which * NHD + head[nt]) * NTOK + i) * HDD + dd[nt]] = f2b(v);
      }
    }
}

// ---------------------------------------------------------------------------
// Kernel 3: transpose V: qkvb[2][head][n][d] -> vtb[head][d][n]
__global__ __launch_bounds__(256)
void k_vt(const short* __restrict__ qkvb, short* __restrict__ vtb) {
  const int head = blockIdx.y;
  const int n0 = blockIdx.x * 64;
  const short* vg = qkvb + ((size_t)(2 * NHD + head)) * NTOK * HDD;
  __shared__ short T[64][68];
  const int t = threadIdx.x;
#pragma unroll
  for (int rp = 0; rp < 4; ++rp) {
    int f = t + 256 * rp;
    int n = f >> 4, c4 = (f & 15) * 4;
    *(short4*)&T[n][c4] = *(const short4*)&vg[(size_t)(n0 + n) * HDD + c4];
  }
  __syncthreads();
#pragma unroll
  for (int rp = 0; rp < 4; ++rp) {
    int f = t + 256 * rp;
    int d = f >> 4, n4 = (f & 15) * 4;
    short4 o;
    o.x = T[n4 + 0][d]; o.y = T[n4 + 1][d];
    o.z = T[n4 + 2][d]; o.w = T[n4 + 3][d];
    *(short4*)&vtb[((size_t)head * HDD + d) * NTOK + n0 + n4] = o;
  }
}

// ---------------------------------------------------------------------------
// Kernel 4: 32x32x16-MFMA flash attention, swapped operands (S^T / O^T).
// grid (64 qblocks, 12 heads), 256 threads = 4 waves: wave w = (kh=w>>1, qh=w&1).
// Each lane owns ONE q column (q = qh*32 + lane&31); softmax entirely in
// registers; P^T B-frags built with one shfl_xor(32) exchange -> no Ps LDS.
//
// 32x32x16 layouts: A[m=lane&31][k=8*(lane>>5)+j]; B[k=8*(lane>>5)+j][n=lane&31]
// C/D: col=lane&31, row=(reg&3)+8*(reg>>2)+4*(lane>>5)   [m74/m101]
//
// LDS (shorts): Ks[64][72]@0, Vt[64][72]@4608, bHb[64][64]@9216,
//               tbuf[64][66]@13312, psb f32[64]@17536
// overlays: RW[128][72]@0, M^T[128][64]@0, RH[64][72]@4608, obuf f32[64][66]@0
__global__ __launch_bounds__(256)
void k_attn3(const short* __restrict__ qkvb, const short* __restrict__ vtb,
             const float* __restrict__ relh, const float* __restrict__ relw,
             short* __restrict__ attnb) {
  const int head = blockIdx.y;
  const int hq = blockIdx.x;
  const int n0 = hq * 64;

  __shared__ short sm[17664];
  short* Ks   = sm;
  short* Vt   = sm + 4608;
  short* bHb  = sm + 9216;
  short* tbuf = sm + 13312;
  float* psb  = (float*)(sm + 17536);
  float* obuf = (float*)sm;

  const short* qg  = qkvb + (size_t)(0 * NHD + head) * NTOK * HDD;
  const short* kg  = qkvb + (size_t)(1 * NHD + head) * NTOK * HDD;
  const short* vtg = vtb + (size_t)head * HDD * NTOK;

  const int t = threadIdx.x;
  const int w = t >> 6, lane = t & 63;
  const int l31 = lane & 31, h = lane >> 5;
  const int kh = w >> 1, qh = w & 1;
  const int q = qh * 32 + l31;

  // staging ownership: 2 rows x 8 shorts each of K and Vt
  const int sa0 = t >> 3, sc0 = (t & 7) * 8, sa1 = sa0 + 32;

  // tile-0 prefetch (consumed at loop kt=0)
  s16x8 kr0 = *(const s16x8*)&kg[(size_t)sa0 * HDD + sc0];
  s16x8 kr1 = *(const s16x8*)&kg[(size_t)sa1 * HDD + sc0];
  s16x8 vr0 = *(const s16x8*)&vtg[(size_t)sa0 * NTOK + sc0];
  s16x8 vr1 = *(const s16x8*)&vtg[(size_t)sa1 * NTOK + sc0];

  // Q B-fragments (persist all kernel): qb[s] = Q[q][s*16 + 8h + j]
  s16x8 qb[4];
#pragma unroll
  for (int s = 0; s < 4; ++s)
    qb[s] = *(const s16x8*)&qg[(size_t)(n0 + q) * HDD + s * 16 + 8 * h];

  // ---- stage RW (127 rows, bf16) into [128][72] overlay ----
#pragma unroll
  for (int rp = 0; rp < 4; ++rp) {
    int f = t + 256 * rp;
    int d = f >> 3, c = (f & 7) * 8;
    float4 v0 = make_float4(0, 0, 0, 0), v1 = v0;
    if (d < 127) {
      const float* s_ = relw + (size_t)d * HDD + c;
      v0 = *(const float4*)s_; v1 = *(const float4*)(s_ + 4);
    }
    short4 b0, b1;
    b0.x = f2b(v0.x); b0.y = f2b(v0.y); b0.z = f2b(v0.z); b0.w = f2b(v0.w);
    b1.x = f2b(v1.x); b1.y = f2b(v1.y); b1.z = f2b(v1.z); b1.w = f2b(v1.w);
    *(short4*)&sm[d * 72 + c] = b0;
    *(short4*)&sm[d * 72 + c + 4] = b1;
  }
  __syncthreads();

  // ---- M^T = RW @ Q^T (rows d, cols q); wave covers d tiles 2kh, 2kh+1 ----
  f32x16 mc0 = (f32x16)(0.f), mc1 = (f32x16)(0.f);
#pragma unroll
  for (int s = 0; s < 4; ++s) {
    s16x8 a0 = *(const s16x8*)&sm[((kh * 2) * 32 + l31) * 72 + s * 16 + 8 * h];
    s16x8 a1 = *(const s16x8*)&sm[((kh * 2 + 1) * 32 + l31) * 72 + s * 16 + 8 * h];
    mc0 = MFMA32(a0, qb[s], mc0);
    mc1 = MFMA32(a1, qb[s], mc1);
  }
  __syncthreads();
  // write M^T bf16 [128][64] over the RW area
#pragma unroll
  for (int reg = 0; reg < 16; ++reg) {
    int dl = (reg & 3) + 8 * (reg >> 2) + 4 * h;
    sm[(kh * 64 + dl) * 64 + q] = f2b(mc0[reg]);
    sm[(kh * 64 + 32 + dl) * 64 + q] = f2b(mc1[reg]);
  }
  __syncthreads();

  // bwl2[reg] = bias_w(q, key_local64) * log2(e); key fixed per reg slot
  float bwl2[16];
#pragma unroll
  for (int reg = 0; reg < 16; ++reg) {
    int kl64 = kh * 32 + (reg & 3) + 8 * (reg >> 2) + 4 * h;
    int dneed = q - kl64 + 63;  // always in [0,126]
    bwl2[reg] = b2f(sm[dneed * 64 + q]) * 1.44269504f;
  }
  __syncthreads();

  // ---- stage RH rows (relh[hq+63-kt]) into Vt area [64][72] ----
#pragma unroll
  for (int rp = 0; rp < 2; ++rp) {
    int f = t + 256 * rp;
    int kt = f >> 3, c = (f & 7) * 8;
    const float* s_ = relh + (size_t)(hq + 63 - kt) * HDD + c;
    float4 v0 = *(const float4*)s_, v1 = *(const float4*)(s_ + 4);
    short4 b0, b1;
    b0.x = f2b(v0.x); b0.y = f2b(v0.y); b0.z = f2b(v0.z); b0.w = f2b(v0.w);
    b1.x = f2b(v1.x); b1.y = f2b(v1.y); b1.z = f2b(v1.z); b1.w = f2b(v1.w);
    *(short4*)&Vt[kt * 72 + c] = b0;
    *(short4*)&Vt[kt * 72 + c + 4] = b1;
  }
  __syncthreads();

  // ---- bH^T = RH @ Q^T; wave covers kt rows kh*32.. ----
  f32x16 hc = (f32x16)(0.f);
#pragma unroll
  for (int s = 0; s < 4; ++s) {
    s16x8 a = *(const s16x8*)&Vt[(kh * 32 + l31) * 72 + s * 16 + 8 * h];
    hc = MFMA32(a, qb[s], hc);
  }
#pragma unroll
  for (int reg = 0; reg < 16; ++reg) {
    int ktl = kh * 32 + (reg & 3) + 8 * (reg >> 2) + 4 * h;
    bHb[ktl * 64 + q] = f2b(hc[reg]);
  }
  // (loop's first barrier publishes bHb and retires RH reads)

  float ps = 0.f;
  f32x16 oc0 = (f32x16)(0.f), oc1 = (f32x16)(0.f);

  for (int kt = 0; kt < 64; ++kt) {
    __syncthreads();
    *(s16x8*)&Ks[sa0 * 72 + sc0] = kr0;
    *(s16x8*)&Ks[sa1 * 72 + sc0] = kr1;
    *(s16x8*)&Vt[sa0 * 72 + sc0] = vr0;
    *(s16x8*)&Vt[sa1 * 72 + sc0] = vr1;
    __syncthreads();
    if (kt < 63) {
      const int nk = (kt + 1) * 64;
      kr0 = *(const s16x8*)&kg[(size_t)(nk + sa0) * HDD + sc0];
      kr1 = *(const s16x8*)&kg[(size_t)(nk + sa1) * HDD + sc0];
      vr0 = *(const s16x8*)&vtg[(size_t)sa0 * NTOK + nk + sc0];
      vr1 = *(const s16x8*)&vtg[(size_t)sa1 * NTOK + nk + sc0];
    }

    // S^T quadrant: keys kh*32..+31 (rows), q cols; 4 k-steps over c
    f32x16 sc_ = (f32x16)(0.f);
#pragma unroll
    for (int s = 0; s < 4; ++s) {
      s16x8 a = *(const s16x8*)&Ks[(kh * 32 + l31) * 72 + s * 16 + 8 * h];
      sc_ = MFMA32(a, qb[s], sc_);
    }

    // softmax, all per-lane (fixed q): p = 2^(S*log2e/8 + (bh+bw)*log2e)
    float bhl2 = b2f(bHb[kt * 64 + q]) * 1.44269504f;
    float sv[16];
#pragma unroll
    for (int reg = 0; reg < 16; ++reg)
      sv[reg] = exp2f(fmaf(0.18033688f, sc_[reg], bhl2 + bwl2[reg]));
#pragma unroll
    for (int reg = 0; reg < 16; ++reg) ps += sv[reg];

    // pack bf16 pairs: pk[i] holds local keys (pair 4*(i>>1)+(i&1)+2h)
    unsigned pk[8], sw[8];
#pragma unroll
    for (int i = 0; i < 8; ++i) {
      int rl = 4 * (i >> 1) + 2 * (i & 1);
      unsigned lo = __float_as_uint(sv[rl]) >> 16;
      unsigned hi = __float_as_uint(sv[rl + 1]) & 0xFFFF0000u;
      pk[i] = hi | lo;
    }
#pragma unroll
    for (int i = 0; i < 8; ++i)
      sw[i] = (unsigned)__shfl_xor((int)pk[i], 32, 64);

    // O^T += V^T @ P^T ; B-frag words selected per half
#pragma unroll
    for (int s2 = 0; s2 < 2; ++s2) {
      union { unsigned u[4]; s16x8 v; } B;
      B.u[0] = h ? sw[4 * s2 + 2] : pk[4 * s2 + 0];
      B.u[1] = h ? sw[4 * s2 + 3] : pk[4 * s2 + 1];
      B.u[2] = h ? pk[4 * s2 + 2] : sw[4 * s2 + 0];
      B.u[3] = h ? pk[4 * s2 + 3] : sw[4 * s2 + 1];
      s16x8 a0 = *(const s16x8*)&Vt[l31 * 72 + kh * 32 + s2 * 16 + 8 * h];
      s16x8 a1 = *(const s16x8*)&Vt[(32 + l31) * 72 + kh * 32 + s2 * 16 + 8 * h];
      oc0 = MFMA32(a0, B.v, oc0);
      oc1 = MFMA32(a1, B.v, oc1);
    }
  }

  // ---- epilogue: combine kh halves, divide by row sum, transpose, store ----
  __syncthreads();
  ps += __shfl_xor(ps, 32, 64);
  if (kh == 1) {
#pragma unroll
    for (int reg = 0; reg < 16; ++reg) {
      int dl = (reg & 3) + 8 * (reg >> 2) + 4 * h;
      obuf[dl * 66 + q] = oc0[reg];
      obuf[(32 + dl) * 66 + q] = oc1[reg];
    }
    if (lane < 32) psb[q] = ps;
  }
  __syncthreads();
  if (kh == 0) {
    float inv = 1.f / (ps + psb[q]);
#pragma unroll
    for (int reg = 0; reg < 16; ++reg) {
      int dl = (reg & 3) + 8 * (reg >> 2) + 4 * h;
      tbuf[dl * 66 + q] = f2b((oc0[reg] + obuf[dl * 66 + q]) * inv);
      tbuf[(32 + dl) * 66 + q] = f2b((oc1[reg] + obuf[(32 + dl) * 66 + q]) * inv);
    }
  }
  __syncthreads();
  {
    int qq = t >> 2, seg = t & 3;
    unsigned wds[8];
#pragma unroll
    for (int m = 0; m < 8; ++m) {
      unsigned lo = (unsigned short)tbuf[(seg * 16 + 2 * m) * 66 + qq];
      unsigned hi = (unsigned short)tbuf[(seg * 16 + 2 * m + 1) * 66 + qq];
      wds[m] = lo | (hi << 16);
    }
    short* dst = attnb + (size_t)(n0 + qq) * DIMD + head * 64 + seg * 16;
    *(int4*)dst = *(int4*)&wds[0];
    *(int4*)(dst + 8) = *(int4*)&wds[4];
  }
}

// ---------------------------------------------------------------------------
// Kernel 5: bf16 MFMA proj: out = attn @ Wp^T + bp (fp32 out)
__global__ __launch_bounds__(256)
void k_proj(const short* __restrict__ ab, const short* __restrict__ wpb,
            const float* __restrict__ bp, float* __restrict__ out) {
  const int j0 = blockIdx.x * 64;
  const int i0 = blockIdx.y * 128;
  __shared__ short As[128 * 32];
  __shared__ short Bs[64 * 32];
  const int t = threadIdx.x, lane = t & 63, w = t >> 6;
  const int l15 = lane & 15, quad = lane >> 4;
  const int wm = w >> 1, wn = w & 1;

  f32x4 acc[4][2];
#pragma unroll
  for (int a = 0; a < 4; ++a)
#pragma unroll
    for (int b = 0; b < 2; ++b) acc[a][b] = (f32x4){0.f, 0.f, 0.f, 0.f};

  for (int kk = 0; kk < DIMD; kk += 32) {
    __syncthreads();
#pragma unroll
    for (int rep = 0; rep < 2; ++rep) {
      int c = rep * 256 + w * 64 + lane;
      gl_lds16(ab + (size_t)(i0 + (c >> 2)) * DIMD + kk + (c & 3) * 8,
               &As[(rep * 256 + w * 64) * 8]);
    }
    {
      gl_lds16(wpb + (size_t)(j0 + ((w * 64 + lane) >> 2)) * DIMD + kk +
                   ((w * 64 + lane) & 3) * 8,
               &Bs[(w * 64) * 8]);
    }
    __syncthreads();
    s16x8 af[4], bf[2];
#pragma unroll
    for (int mt = 0; mt < 4; ++mt)
      af[mt] = *(const s16x8*)&As[(wm * 64 + mt * 16 + l15) * 32 + quad * 8];
#pragma unroll
    for (int nt = 0; nt < 2; ++nt)
      bf[nt] = *(const s16x8*)&Bs[(wn * 32 + nt * 16 + l15) * 32 + quad * 8];
#pragma unroll
    for (int mt = 0; mt < 4; ++mt)
#pragma unroll
      for (int nt = 0; nt < 2; ++nt)
        acc[mt][nt] = MFMA16(af[mt], bf[nt], acc[mt][nt]);
  }

#pragma unroll
  for (int mt = 0; mt < 4; ++mt)
#pragma unroll
    for (int r = 0; r < 4; ++r) {
      const int i = i0 + wm * 64 + mt * 16 + quad * 4 + r;
#pragma unroll
      for (int nt = 0; nt < 2; ++nt) {
        const int j = j0 + wn * 32 + nt * 16 + l15;
        out[(size_t)i * DIMD + j] = acc[mt][nt][r] + bp[j];
      }
    }
}

// ---------------------------------------------------------------------------
extern "C" void kernel_launch(void* const* d_in, const int* in_sizes, int n_in,
                              void* d_out, int out_size, void* d_ws, size_t ws_size,
                              hipStream_t stream) {
  (void)in_sizes; (void)n_in; (void)out_size; (void)ws_size;
  const float* x    = (const float*)d_in[0];
  const float* Wqkv = (const float*)d_in[1];
  const float* bqkv = (const float*)d_in[2];
  const float* Aq   = (const float*)d_in[3];
  const float* Bq   = (const float*)d_in[4];
  const float* Av   = (const float*)d_in[5];
  const float* Bv   = (const float*)d_in[6];
  const float* relh = (const float*)d_in[7];
  const float* relw = (const float*)d_in[8];
  const float* Wp   = (const float*)d_in[9];
  const float* bp   = (const float*)d_in[10];
  float* out = (float*)d_out;

  float* ws = (float*)d_ws;
  float* xaq  = ws;
  float* xav  = ws + 16384;
  short* xb    = (short*)(ws + 32768);
  short* wqkvb = (short*)(ws + 1605632);
  short* wpb   = (short*)(ws + 2490368);
  short* qkvb  = (short*)(ws + 2785280);
  short* vtb   = (short*)(ws + 7503872);
  short* attnb = (short*)(ws + 9076736);

  k_conv<<<dim3(2304), dim3(256), 0, stream>>>(Wqkv, Wp, wqkvb, wpb);
  k_lora<<<dim3(NTOK), dim3(64), 0, stream>>>(x, Aq, Av, xaq, xav, xb);
  k_qkv<<<dim3(18, 32), dim3(256), 0, stream>>>(xb, wqkvb, bqkv, Bq, Bv, xaq,
                                                xav, qkvb);
  k_vt<<<dim3(64, NHD), dim3(256), 0, stream>>>(qkvb, vtb);
  k_attn3<<<dim3(64, NHD), dim3(256), 0, stream>>>(qkvb, vtb, relh, relw, attnb);
  k_proj<<<dim3(12, 32), dim3(256), 0, stream>>>(attnb, wpb, bp, out);
}